// Round 1
// baseline (225.108 us; speedup 1.0000x reference)
//
#include <hip/hip_runtime.h>
#include <hip/hip_bf16.h>

#define KTAG 52
#define START_TAG 50
#define STOP_TAG 51
#define TMAX 512

// One wave (64 lanes) per batch element. Lane i owns tag i (lanes 52..63 inert).
// Linear-domain scaled forward: beta[j] = exp(alpha[j] - M), step = 52x52 matvec
// with E[i][j] = exp(trans[i][j]) held in VGPRs, beta broadcast via LDS.
__global__ __launch_bounds__(64) void crf_nll_kernel(
    const float* __restrict__ logits,   // [B, T, K]
    const float* __restrict__ trans,    // [K, K]  trans[to][from]
    const int*   __restrict__ labels,   // [B, T]
    const int*   __restrict__ lens,     // [B]
    float* __restrict__ out)            // [B]
{
    constexpr float L2E = 1.4426950408889634f;
    constexpr float LN2 = 0.6931471805599453f;

    const int b    = blockIdx.x;
    const int lane = threadIdx.x;          // 0..63
    const bool active = lane < KTAG;
    const int len = lens[b];               // >= 1 by construction

    __shared__ __align__(16) float sbeta[64];

    // ---- Load this lane's row of E = exp(trans) into registers (once) ----
    float Erow[KTAG];
    {
        const float* trow = trans + (size_t)(active ? lane : 0) * KTAG;
        #pragma unroll
        for (int j = 0; j < KTAG; ++j)
            Erow[j] = active ? exp2f(trow[j] * L2E) : 0.0f;
    }

    // per-lane logit pointer: logits[b][t][lane]
    const float* lgp = logits + (size_t)b * TMAX * KTAG + (active ? lane : 0);

    // beta init: one-hot at START (exp(-10000) == 0 in fp32, matches reference)
    float beta = (lane == START_TAG) ? 1.0f : 0.0f;
    sbeta[lane] = beta;
    __syncthreads();

    float M2 = 0.0f;   // running log2 scale

    auto lgt = [&](int t) -> float {
        int tc = t < TMAX ? t : (TMAX - 1);   // clamped prefetch, always in-bounds
        return lgp[tc * KTAG];
    };

    // prefetch depth 4
    float l0 = lgt(0), l1 = lgt(1), l2 = lgt(2), l3 = lgt(3);

    #pragma unroll 4
    for (int t = 0; t < len; ++t) {
        float lg = l0;
        l0 = l1; l1 = l2; l2 = l3; l3 = lgt(t + 4);

        // Pipelined rescale: every 4th iter, max-reduce the *current* stored beta
        // (independent of this iter's matvec -> overlaps with the FMAs below).
        float scl = 1.0f;
        if ((t & 3) == 0 && t > 0) {
            float m = beta;
            #pragma unroll
            for (int off = 32; off; off >>= 1)
                m = fmaxf(m, __shfl_xor(m, off));
            M2 += log2f(m);
            scl = 1.0f / m;
        }

        float e = exp2f(lg * L2E);

        // matvec: acc[i] = sum_j E[i][j] * beta[j]   (13 x b128 broadcast reads)
        float a0 = 0.f, a1 = 0.f, a2 = 0.f, a3 = 0.f;
        #pragma unroll
        for (int p = 0; p < 13; ++p) {
            float4 bv = *reinterpret_cast<const float4*>(&sbeta[p * 4]);
            a0 = fmaf(Erow[4*p+0], bv.x, a0);
            a1 = fmaf(Erow[4*p+1], bv.y, a1);
            a2 = fmaf(Erow[4*p+2], bv.z, a2);
            a3 = fmaf(Erow[4*p+3], bv.w, a3);
        }
        float bn = ((a0 + a1) + (a2 + a3)) * e * scl;   // lanes >= K: Erow==0 -> 0

        sbeta[lane] = bn;
        __syncthreads();    // single-wave barrier: prevents LDS read hoisting
        beta = bn;
    }

    // ---- partition = LN2 * (M2 + log2(sum_i beta[i] * exp(trans[STOP][i]))) ----
    float es = active ? trans[(size_t)STOP_TAG * KTAG + lane] : 0.0f;
    float contrib = beta * exp2f(es * L2E);
    float s = contrib;
    #pragma unroll
    for (int off = 32; off; off >>= 1) s += __shfl_xor(s, off);
    float partition = LN2 * (M2 + log2f(s));

    // ---- gold-path scores (t-parallel across lanes) ----
    const int*   labp = labels + (size_t)b * TMAX;
    const float* lgb  = logits + (size_t)b * TMAX * KTAG;
    float em = 0.0f, tr = 0.0f;
    for (int t = lane; t < len; t += 64) {
        int lab = labp[t];
        em += lgb[t * KTAG + lab];
        int prv = (t == 0) ? START_TAG : labp[t - 1];
        tr += trans[lab * KTAG + prv];
    }
    if (lane == 0)
        tr += trans[STOP_TAG * KTAG + labp[len - 1]];

    #pragma unroll
    for (int off = 32; off; off >>= 1) {
        em += __shfl_xor(em, off);
        tr += __shfl_xor(tr, off);
    }

    if (lane == 0) out[b] = partition + em - tr;
}

extern "C" void kernel_launch(void* const* d_in, const int* in_sizes, int n_in,
                              void* d_out, int out_size, void* d_ws, size_t ws_size,
                              hipStream_t stream) {
    const float* logits = (const float*)d_in[0];
    const float* trans  = (const float*)d_in[1];
    const int*   labels = (const int*)d_in[2];
    const int*   lens   = (const int*)d_in[3];
    float* out = (float*)d_out;

    const int B = in_sizes[3];   // lens element count
    crf_nll_kernel<<<dim3(B), dim3(64), 0, stream>>>(logits, trans, labels, lens, out);
}

// Round 2
// 116.653 us; speedup vs baseline: 1.9297x; 1.9297x over previous
//
#include <hip/hip_runtime.h>
#include <hip/hip_bf16.h>

#define KTAG 52
#define START_TAG 50
#define STOP_TAG 51
#define TMAX 512

// Broadcast lane l's float to all lanes via v_readlane (imm lane, SGPR result).
__device__ __forceinline__ float rdlane(float v, int l) {
    return __int_as_float(__builtin_amdgcn_readlane(__float_as_int(v), l));
}

// One wave (64 lanes) per batch element. Lane i owns tag i (lanes 52..63 inert).
// Linear-domain scaled forward: beta[j] = exp(alpha[j] - M). Step = 52x52 matvec
// with E[i][j] = exp(trans[i][j]) in VGPRs; beta broadcast via v_readlane.
// NO LDS, NO barriers -> global logit prefetch stays in flight across steps.
__global__ __launch_bounds__(64) void crf_nll_kernel(
    const float* __restrict__ logits,   // [B, T, K]
    const float* __restrict__ trans,    // [K, K]  trans[to][from]
    const int*   __restrict__ labels,   // [B, T]
    const int*   __restrict__ lens,     // [B]
    float* __restrict__ out)            // [B]
{
    constexpr float L2E = 1.4426950408889634f;
    constexpr float LN2 = 0.6931471805599453f;

    const int b    = blockIdx.x;
    const int lane = threadIdx.x;          // 0..63
    const bool active = lane < KTAG;
    const int len = lens[b];               // >= 1

    // ---- E = exp(trans): this lane's row, in registers ----
    float Erow[KTAG];
    {
        const float* trow = trans + (size_t)(active ? lane : 0) * KTAG;
        #pragma unroll
        for (int j = 0; j < KTAG; ++j)
            Erow[j] = active ? exp2f(trow[j] * L2E) : 0.0f;
    }

    const float* lgp = logits + (size_t)b * TMAX * KTAG + (active ? lane : 0);

    // beta init: one-hot at START (exp(-10000) == 0 in fp32, matches reference)
    float beta = (lane == START_TAG) ? 1.0f : 0.0f;
    float M2 = 0.0f;   // running log2 scale

    auto lgt = [&](int t) -> float {
        int tc = t < TMAX ? t : (TMAX - 1);   // clamped prefetch, always in-bounds
        return lgp[tc * KTAG];
    };

    // One forward step: beta_new[i] = (sum_j E[i][j]*beta[j]) * exp(logit_i) * scl
    auto STEP = [&](float lg, float scl) {
        float e = exp2f(lg * L2E) * scl;
        float a0 = 0.f, a1 = 0.f, a2 = 0.f, a3 = 0.f;
        #pragma unroll
        for (int j = 0; j < 13; ++j) {
            a0 = fmaf(Erow[4*j+0], rdlane(beta, 4*j+0), a0);
            a1 = fmaf(Erow[4*j+1], rdlane(beta, 4*j+1), a1);
            a2 = fmaf(Erow[4*j+2], rdlane(beta, 4*j+2), a2);
            a3 = fmaf(Erow[4*j+3], rdlane(beta, 4*j+3), a3);
        }
        beta = ((a0 + a1) + (a2 + a3)) * e;
    };

    // prefetch depth 4
    float l0 = lgt(0), l1 = lgt(1), l2 = lgt(2), l3 = lgt(3);

    int t = 0;
    // main loop: chunks of 4 steps; rescale once per chunk via lane-0 beta
    // (within 2^~30 of beta_max -> safe with 4-step worst-case growth ~2^64)
    while (t + 4 <= len) {
        float n0 = lgt(t + 4), n1 = lgt(t + 5), n2 = lgt(t + 6), n3 = lgt(t + 7);
        float scl = 1.0f;
        if (t > 0) {                         // uniform branch
            float m = rdlane(beta, 0);       // beta[0] > 0 for t >= 1
            M2 += log2f(m);
            scl = 1.0f / m;
        }
        STEP(l0, scl);
        STEP(l1, 1.0f);
        STEP(l2, 1.0f);
        STEP(l3, 1.0f);
        l0 = n0; l1 = n1; l2 = n2; l3 = n3;
        t += 4;
    }
    // remainder (0..3 steps), logits already prefetched in l0..l2
    if (t < len) {
        float scl = 1.0f;
        if (t > 0) {
            float m = rdlane(beta, 0);
            M2 += log2f(m);
            scl = 1.0f / m;
        }
        STEP(l0, scl); ++t;
        if (t < len) { STEP(l1, 1.0f); ++t; }
        if (t < len) { STEP(l2, 1.0f); ++t; }
    }

    // ---- partition = LN2 * (M2 + log2(sum_i beta[i] * exp(trans[STOP][i]))) ----
    float es = active ? trans[(size_t)STOP_TAG * KTAG + lane] : 0.0f;
    float contrib = active ? beta * exp2f(es * L2E) : 0.0f;
    float s = contrib;
    #pragma unroll
    for (int off = 32; off; off >>= 1) s += __shfl_xor(s, off);
    float partition = LN2 * (M2 + log2f(s));

    // ---- gold-path scores (t-parallel across lanes) ----
    const int*   labp = labels + (size_t)b * TMAX;
    const float* lgb  = logits + (size_t)b * TMAX * KTAG;
    float em = 0.0f, tr = 0.0f;
    for (int tt = lane; tt < len; tt += 64) {
        int lab = labp[tt];
        em += lgb[tt * KTAG + lab];
        int prv = (tt == 0) ? START_TAG : labp[tt - 1];
        tr += trans[lab * KTAG + prv];
    }
    if (lane == 0)
        tr += trans[STOP_TAG * KTAG + labp[len - 1]];

    #pragma unroll
    for (int off = 32; off; off >>= 1) {
        em += __shfl_xor(em, off);
        tr += __shfl_xor(tr, off);
    }

    if (lane == 0) out[b] = partition + em - tr;
}

extern "C" void kernel_launch(void* const* d_in, const int* in_sizes, int n_in,
                              void* d_out, int out_size, void* d_ws, size_t ws_size,
                              hipStream_t stream) {
    const float* logits = (const float*)d_in[0];
    const float* trans  = (const float*)d_in[1];
    const int*   labels = (const int*)d_in[2];
    const int*   lens   = (const int*)d_in[3];
    float* out = (float*)d_out;

    const int B = in_sizes[3];   // lens element count
    crf_nll_kernel<<<dim3(B), dim3(64), 0, stream>>>(logits, trans, labels, lens, out);
}